// Round 3
// baseline (299.751 us; speedup 1.0000x reference)
//
#include <hip/hip_runtime.h>

#define N_IMG   1024
#define N_VIEWS 90
#define CENTER  512
#define TILE    64
#define NYB     (N_IMG / TILE)      // 16 y-blocks
#define MAXH    92
#define MAXSTRIDE 97
#define LDS_WORDS (MAXH * MAXSTRIDE)  // 8924 words = 35.7 KB -> 4 blocks/CU

// x_in =  ca*X + sa*Y + cx,  cx = CENTER*(1 - ca - sa)
// y_in = -sa*X + ca*Y + cy,  cy = CENTER*(1 - ca + sa)
// Fixed fmaf chain: corner extremes == sample extremes (monotone per variable),
// so the bbox from corners bounds every sample's floor exactly.
__device__ __forceinline__ void map_coords(float ca, float sa, float cx, float cy,
                                           float Xf, float Yf,
                                           float& x_in, float& y_in) {
    const float fx0 = fmaf(ca, Xf, cx);
    const float fy0 = fmaf(-sa, Xf, cy);
    x_in = fmaf(sa, Yf, fx0);
    y_in = fmaf(ca, Yf, fy0);
}

// STRIDE=95 (theta<90: bank ~ x-y, lane step |ca+sa|>=1)
// STRIDE=97 (theta>=90: bank ~ x+y, lane step |ca-sa|>=1)
template<int STRIDE>
__global__ __launch_bounds__(256) void radon_tile(const float* __restrict__ img,
                                                  const float* __restrict__ theta,
                                                  float* __restrict__ partial,
                                                  float* __restrict__ out,
                                                  int a0, int mode) {
    const int a  = a0 + blockIdx.z;
    const int X0 = blockIdx.x * TILE;
    const int Y0 = blockIdx.y * TILE;
    const int tid  = threadIdx.x;
    const int lane = tid & 63;
    const int wv   = tid >> 6;

    float* __restrict__ pslot = partial + ((size_t)(a * NYB + blockIdx.y) << 10) + X0;

    const float ang = theta[a] * 0.017453292519943295f;
    float sa, ca;
    __sincosf(ang, &sa, &ca);
    const float cx = (float)CENTER * (1.0f - ca - sa);
    const float cy = (float)CENTER * (1.0f - ca + sa);

    // ---- bbox from the 4 tile corners ----
    float x00, y00, x01, y01, x10, y10, x11, y11;
    map_coords(ca, sa, cx, cy, (float)X0,        (float)Y0,        x00, y00);
    map_coords(ca, sa, cx, cy, (float)(X0 + 63), (float)Y0,        x01, y01);
    map_coords(ca, sa, cx, cy, (float)X0,        (float)(Y0 + 63), x10, y10);
    map_coords(ca, sa, cx, cy, (float)(X0 + 63), (float)(Y0 + 63), x11, y11);
    const float xmin = fminf(fminf(x00, x01), fminf(x10, x11));
    const float xmax = fmaxf(fmaxf(x00, x01), fmaxf(x10, x11));
    const float ymin = fminf(fminf(y00, y01), fminf(y10, y11));
    const float ymax = fmaxf(fmaxf(y00, y01), fmaxf(y10, y11));

    const int ix0_raw = (int)floorf(xmin);
    const int ix1_raw = (int)floorf(xmax) + 1;
    const int iy0_raw = (int)floorf(ymin);
    const int iy1_raw = (int)floorf(ymax) + 1;

    const int ix0 = max(0, ix0_raw);
    const int ix1 = min(N_IMG - 1, ix1_raw);
    const int iy0 = max(0, iy0_raw);
    const int iy1 = min(N_IMG - 1, iy1_raw);

    if (ix1 < ix0 || iy1 < iy0) {          // tile maps fully outside image
        if (mode == 0) { if (tid < 64) pslot[tid] = 0.0f; }
        return;                             // mode 1: out pre-zeroed
    }

    const int h = iy1 - iy0 + 1;           // <= 92
    const int W = ix1 - ix0 + 1;           // <= 92

    __shared__ float tile[LDS_WORDS];
    __shared__ float red[4][64];

    // ---- stage bbox into LDS: lane = consecutive dword -> conflict-free writes,
    //      coalesced 256B/wave global reads ----
    for (int r = wv; r < h; r += 4) {
        const float* __restrict__ rowp = img + (size_t)(iy0 + r) * N_IMG + ix0;
        float* dst = tile + r * STRIDE;
        for (int c = lane; c < W; c += 64) dst[c] = rowp[c];
    }
    __syncthreads();

    // ---- bilinear samples from LDS ----
    const int X = X0 + lane;
    const float Xf  = (float)X;
    const float fx0 = fmaf(ca, Xf, cx);
    const float fy0 = fmaf(-sa, Xf, cy);
    const int Ybase = Y0 + wv * 16;
    float acc = 0.0f;

    const bool interior = (ix0_raw >= 0) && (ix1_raw <= N_IMG - 1) &&
                          (iy0_raw >= 0) && (iy1_raw <= N_IMG - 1);
    const int base = -(iy0 * STRIDE + ix0);

    if (interior) {
        #pragma unroll
        for (int i = 0; i < 16; ++i) {
            const float Yf   = (float)(Ybase + i);
            const float x_in = fmaf(sa, Yf, fx0);
            const float y_in = fmaf(ca, Yf, fy0);
            const float x0f = floorf(x_in);
            const float y0f = floorf(y_in);
            const float wx  = x_in - x0f;
            const float wy  = y_in - y0f;
            const int li = (int)y0f * STRIDE + (int)x0f + base;
            const float t00 = tile[li];
            const float t01 = tile[li + 1];
            const float t10 = tile[li + STRIDE];
            const float t11 = tile[li + STRIDE + 1];
            const float top = fmaf(wx, t01 - t00, t00);
            const float bot = fmaf(wx, t11 - t10, t10);
            acc += fmaf(wy, bot - top, top);
        }
    } else {
        #pragma unroll
        for (int i = 0; i < 16; ++i) {
            const float Yf   = (float)(Ybase + i);
            const float x_in = fmaf(sa, Yf, fx0);
            const float y_in = fmaf(ca, Yf, fy0);
            const float x0f = floorf(x_in);
            const float y0f = floorf(y_in);
            const float wx  = x_in - x0f;
            const float wy  = y_in - y0f;
            const int x0 = (int)x0f;
            const int y0 = (int)y0f;
            const int x0c = min(max(x0,     0), N_IMG - 1);
            const int x1c = min(max(x0 + 1, 0), N_IMG - 1);
            const int y0c = min(max(y0,     0), N_IMG - 1);
            const int y1c = min(max(y0 + 1, 0), N_IMG - 1);
            const float wxa = (x0     >= 0 && x0     < N_IMG) ? (1.0f - wx) : 0.0f;
            const float wxb = (x0 + 1 >= 0 && x0 + 1 < N_IMG) ? wx          : 0.0f;
            const float wya = (y0     >= 0 && y0     < N_IMG) ? (1.0f - wy) : 0.0f;
            const float wyb = (y0 + 1 >= 0 && y0 + 1 < N_IMG) ? wy          : 0.0f;
            const int r0 = (y0c - iy0) * STRIDE - ix0;
            const int r1 = (y1c - iy0) * STRIDE - ix0;
            const float t00 = tile[r0 + x0c];
            const float t01 = tile[r0 + x1c];
            const float t10 = tile[r1 + x0c];
            const float t11 = tile[r1 + x1c];
            acc += wya * fmaf(wxa, t00, wxb * t01)
                 + wyb * fmaf(wxa, t10, wxb * t11);
        }
    }

    // ---- block reduce; one plain store (mode 0) or atomic (fallback) ----
    red[wv][lane] = acc;
    __syncthreads();
    if (wv == 0) {
        const float s = red[0][lane] + red[1][lane] + red[2][lane] + red[3][lane];
        if (mode == 0) pslot[lane] = s;
        else           atomicAdd(&out[X * N_VIEWS + a], s);
    }
}

__global__ __launch_bounds__(256) void reduce_partials(const float* __restrict__ partial,
                                                       float* __restrict__ out) {
    const int g = blockIdx.x * 256 + threadIdx.x;   // [0, 90*1024)
    const int a = g >> 10;
    const int X = g & 1023;
    float s = 0.0f;
    #pragma unroll
    for (int yb = 0; yb < NYB; ++yb)
        s += partial[((size_t)(a * NYB + yb) << 10) + X];
    out[X * N_VIEWS + a] = s;
}

extern "C" void kernel_launch(void* const* d_in, const int* in_sizes, int n_in,
                              void* d_out, int out_size, void* d_ws, size_t ws_size,
                              hipStream_t stream) {
    const float* img   = (const float*)d_in[0];   // [1024, 1024] f32
    const float* theta = (const float*)d_in[1];   // [90] f32 degrees
    float* out     = (float*)d_out;               // [1024, 90] f32
    float* partial = (float*)d_ws;                // [90][16][1024] f32 partials

    const size_t needed = (size_t)N_VIEWS * NYB * N_IMG * sizeof(float);  // 5.9 MB
    const int mode = (ws_size >= needed) ? 0 : 1;
    if (mode == 1)
        hipMemsetAsync(d_out, 0, (size_t)out_size * sizeof(float), stream);

    dim3 grid(N_IMG / TILE, N_IMG / TILE, N_VIEWS / 2);   // 16 x 16 x 45 per half
    // a in [0,45): theta = 0..88  -> ca > 0  -> stride 95
    radon_tile<95><<<grid, 256, 0, stream>>>(img, theta, partial, out, 0, mode);
    // a in [45,90): theta = 90..178 -> ca <= 0 -> stride 97
    radon_tile<97><<<grid, 256, 0, stream>>>(img, theta, partial, out, 45, mode);

    if (mode == 0)
        reduce_partials<<<(N_VIEWS * N_IMG) / 256, 256, 0, stream>>>(partial, out);
}

// Round 4
// 159.015 us; speedup vs baseline: 1.8850x; 1.8850x over previous
//
#include <hip/hip_runtime.h>

#define N_IMG   1024
#define N_VIEWS 90
#define CENTER  512
#define TILE    64
#define NYB     (N_IMG / TILE)      // 16 y-blocks
#define MAXH    92                  // 63*sqrt(2)+2 slack, rounded up

// x_in =  ca*X + sa*Y + cx,  cx = CENTER*(1 - ca - sa)
// y_in = -sa*X + ca*Y + cy,  cy = CENTER*(1 - ca + sa)
// Fixed fmaf chain: corner extremes == sample extremes (monotone per variable),
// so the bbox from the 4 corners bounds every sample's floor exactly.
__device__ __forceinline__ void map_coords(float ca, float sa, float cx, float cy,
                                           float Xf, float Yf,
                                           float& x_in, float& y_in) {
    const float fx0 = fmaf(ca, Xf, cx);
    const float fy0 = fmaf(-sa, Xf, cy);
    x_in = fmaf(sa, Yf, fx0);
    y_in = fmaf(ca, Yf, fy0);
}

// Async global->LDS DMA, 4 B/lane: lane i loads mem[g + i] (g is per-lane ptr
// here, pre-offset by lane), HW deposits at wave-uniform LDS base l + lane*4.
// No ds_write instructions, no VGPR round-trip.
__device__ __forceinline__ void gload_lds4(const float* g, float* l) {
    __builtin_amdgcn_global_load_lds((const __attribute__((address_space(1))) void*)g,
                                     (__attribute__((address_space(3))) void*)l,
                                     4, 0, 0);
}

// STRIDE=95 (theta<90: bank ~ x-y, lane step |ca+sa| in [1,1.414])
// STRIDE=97 (theta>=90: bank ~ x+y, lane step |ca-sa| in [1,1.414])
template<int STRIDE>
__global__ __launch_bounds__(256) void radon_tile(const float* __restrict__ img,
                                                  const float* __restrict__ theta,
                                                  float* __restrict__ partial,
                                                  float* __restrict__ out,
                                                  int a0, int mode) {
    __shared__ float tile[MAXH * STRIDE];   // <= 35.7 KB
    __shared__ float red[4][64];

    const int a  = a0 + blockIdx.z;
    const int X0 = blockIdx.x * TILE;
    const int Y0 = blockIdx.y * TILE;
    const int tid  = threadIdx.x;
    const int lane = tid & 63;
    const int wv   = tid >> 6;

    float* __restrict__ pslot = partial + ((size_t)(a * NYB + blockIdx.y) << 10) + X0;

    const float ang = theta[a] * 0.017453292519943295f;
    float sa, ca;
    __sincosf(ang, &sa, &ca);
    const float cx = (float)CENTER * (1.0f - ca - sa);
    const float cy = (float)CENTER * (1.0f - ca + sa);

    // ---- bbox from the 4 tile corners ----
    float x00, y00, x01, y01, x10, y10, x11, y11;
    map_coords(ca, sa, cx, cy, (float)X0,        (float)Y0,        x00, y00);
    map_coords(ca, sa, cx, cy, (float)(X0 + 63), (float)Y0,        x01, y01);
    map_coords(ca, sa, cx, cy, (float)X0,        (float)(Y0 + 63), x10, y10);
    map_coords(ca, sa, cx, cy, (float)(X0 + 63), (float)(Y0 + 63), x11, y11);
    const float xmin = fminf(fminf(x00, x01), fminf(x10, x11));
    const float xmax = fmaxf(fmaxf(x00, x01), fmaxf(x10, x11));
    const float ymin = fminf(fminf(y00, y01), fminf(y10, y11));
    const float ymax = fmaxf(fmaxf(y00, y01), fmaxf(y10, y11));

    const int ix0_raw = (int)floorf(xmin);
    const int ix1_raw = (int)floorf(xmax) + 1;
    const int iy0_raw = (int)floorf(ymin);
    const int iy1_raw = (int)floorf(ymax) + 1;

    const int ix0 = max(0, ix0_raw);
    const int ix1 = min(N_IMG - 1, ix1_raw);
    const int iy0 = max(0, iy0_raw);
    const int iy1 = min(N_IMG - 1, iy1_raw);

    if (ix1 < ix0 || iy1 < iy0) {          // tile maps fully outside image
        if (mode == 0) { if (tid < 64) pslot[tid] = 0.0f; }
        return;                             // mode 1: out pre-zeroed
    }

    // ---- column cover by two full-wave 64-dword segments (no exec masking):
    //      A = [a0x, a0x+64), B = [b0x, b0x+64); overlap written twice (same data).
    const int a0x = min(ix0, N_IMG - 64);   // always fully in-image
    const int b0x = max(a0x, ix1 - 63);     // always fully in-image, >= a0x
    const int dB  = b0x - a0x;              // 0..28 -> row width used <= 92 < STRIDE
    const int h   = iy1 - iy0 + 1;          // <= 92

    // ---- stage via async DMA: 2 global_load_lds per row, zero ds_writes ----
    {
        const float* g = img + (size_t)(iy0 + wv) * N_IMG + a0x + lane;
        float* l = tile + wv * STRIDE;
        for (int r = wv; r < h; r += 4) {
            gload_lds4(g, l);
            if (dB > 0) gload_lds4(g + dB, l + dB);
            g += 4 * N_IMG;
            l += 4 * STRIDE;
        }
    }
    __syncthreads();   // drains vmcnt (incl. global_load_lds) before reads

    // ---- bilinear samples from LDS ----
    const int X = X0 + lane;
    const float Xf  = (float)X;
    const float fx0 = fmaf(ca, Xf, cx);
    const float fy0 = fmaf(-sa, Xf, cy);
    const int Ybase = Y0 + wv * 16;
    float acc = 0.0f;

    const bool interior = (ix0_raw >= 0) && (ix1_raw <= N_IMG - 1) &&
                          (iy0_raw >= 0) && (iy1_raw <= N_IMG - 1);
    const int base = -(iy0 * STRIDE + a0x);

    if (interior) {
        #pragma unroll
        for (int i = 0; i < 16; ++i) {
            const float Yf   = (float)(Ybase + i);
            const float x_in = fmaf(sa, Yf, fx0);
            const float y_in = fmaf(ca, Yf, fy0);
            const float x0f = floorf(x_in);
            const float y0f = floorf(y_in);
            const float wx  = x_in - x0f;
            const float wy  = y_in - y0f;
            const int li = (int)y0f * STRIDE + (int)x0f + base;
            const float t00 = tile[li];             // ds_read2 pair (0,1)
            const float t01 = tile[li + 1];
            const float t10 = tile[li + STRIDE];    // ds_read2 pair (S,S+1)
            const float t11 = tile[li + STRIDE + 1];
            const float top = fmaf(wx, t01 - t00, t00);
            const float bot = fmaf(wx, t11 - t10, t10);
            acc += fmaf(wy, bot - top, top);
        }
    } else {
        #pragma unroll
        for (int i = 0; i < 16; ++i) {
            const float Yf   = (float)(Ybase + i);
            const float x_in = fmaf(sa, Yf, fx0);
            const float y_in = fmaf(ca, Yf, fy0);
            const float x0f = floorf(x_in);
            const float y0f = floorf(y_in);
            const float wx  = x_in - x0f;
            const float wy  = y_in - y0f;
            const int x0 = (int)x0f;
            const int y0 = (int)y0f;
            const int x0c = min(max(x0,     0), N_IMG - 1);
            const int x1c = min(max(x0 + 1, 0), N_IMG - 1);
            const int y0c = min(max(y0,     0), N_IMG - 1);
            const int y1c = min(max(y0 + 1, 0), N_IMG - 1);
            const float wxa = (x0     >= 0 && x0     < N_IMG) ? (1.0f - wx) : 0.0f;
            const float wxb = (x0 + 1 >= 0 && x0 + 1 < N_IMG) ? wx          : 0.0f;
            const float wya = (y0     >= 0 && y0     < N_IMG) ? (1.0f - wy) : 0.0f;
            const float wyb = (y0 + 1 >= 0 && y0 + 1 < N_IMG) ? wy          : 0.0f;
            const int r0 = (y0c - iy0) * STRIDE - a0x;
            const int r1 = (y1c - iy0) * STRIDE - a0x;
            const float t00 = tile[r0 + x0c];
            const float t01 = tile[r0 + x1c];
            const float t10 = tile[r1 + x0c];
            const float t11 = tile[r1 + x1c];
            acc += wya * fmaf(wxa, t00, wxb * t01)
                 + wyb * fmaf(wxa, t10, wxb * t11);
        }
    }

    // ---- block reduce; plain store (mode 0) or atomic (fallback) ----
    red[wv][lane] = acc;
    __syncthreads();
    if (wv == 0) {
        const float s = red[0][lane] + red[1][lane] + red[2][lane] + red[3][lane];
        if (mode == 0) pslot[lane] = s;
        else           atomicAdd(&out[X * N_VIEWS + a], s);
    }
}

__global__ __launch_bounds__(256) void reduce_partials(const float* __restrict__ partial,
                                                       float* __restrict__ out) {
    const int g = blockIdx.x * 256 + threadIdx.x;   // [0, 90*1024)
    const int a = g >> 10;
    const int X = g & 1023;
    float s = 0.0f;
    #pragma unroll
    for (int yb = 0; yb < NYB; ++yb)
        s += partial[((size_t)(a * NYB + yb) << 10) + X];
    out[X * N_VIEWS + a] = s;
}

extern "C" void kernel_launch(void* const* d_in, const int* in_sizes, int n_in,
                              void* d_out, int out_size, void* d_ws, size_t ws_size,
                              hipStream_t stream) {
    const float* img   = (const float*)d_in[0];   // [1024, 1024] f32
    const float* theta = (const float*)d_in[1];   // [90] f32 degrees
    float* out     = (float*)d_out;               // [1024, 90] f32
    float* partial = (float*)d_ws;                // [90][16][1024] f32 partials

    const size_t needed = (size_t)N_VIEWS * NYB * N_IMG * sizeof(float);  // 5.9 MB
    const int mode = (ws_size >= needed) ? 0 : 1;
    if (mode == 1)
        hipMemsetAsync(d_out, 0, (size_t)out_size * sizeof(float), stream);

    dim3 grid(N_IMG / TILE, N_IMG / TILE, N_VIEWS / 2);   // 16 x 16 x 45 per half
    // a in [0,45): theta = 0..88   -> ca > 0  -> stride 95
    radon_tile<95><<<grid, 256, 0, stream>>>(img, theta, partial, out, 0, mode);
    // a in [45,90): theta = 90..178 -> ca <= 0 -> stride 97
    radon_tile<97><<<grid, 256, 0, stream>>>(img, theta, partial, out, 45, mode);

    if (mode == 0)
        reduce_partials<<<(N_VIEWS * N_IMG) / 256, 256, 0, stream>>>(partial, out);
}

// Round 5
// 150.658 us; speedup vs baseline: 1.9896x; 1.0555x over previous
//
#include <hip/hip_runtime.h>

#define N_IMG   1024
#define N_VIEWS 90
#define CENTER  512
#define TILE    64
#define NYB     (N_IMG / TILE)      // 16 y-blocks
#define MAXH    92                  // 63*sqrt(2)+2 slack, rounded up
#define MAXS    97
#define NTHREADS 512
#define NWAVES   8

// x_in =  ca*X + sa*Y + cx,  cx = CENTER*(1 - ca - sa)
// y_in = -sa*X + ca*Y + cy,  cy = CENTER*(1 - ca + sa)
// Fixed fmaf chain: corner extremes == sample extremes (monotone per variable),
// so the bbox from the 4 corners bounds every sample's floor exactly.
__device__ __forceinline__ void map_coords(float ca, float sa, float cx, float cy,
                                           float Xf, float Yf,
                                           float& x_in, float& y_in) {
    const float fx0 = fmaf(ca, Xf, cx);
    const float fy0 = fmaf(-sa, Xf, cy);
    x_in = fmaf(sa, Yf, fx0);
    y_in = fmaf(ca, Yf, fy0);
}

// Async global->LDS DMA, 4 B/lane: lane i loads g[i] (g pre-offset by lane),
// HW deposits at wave-uniform LDS base l + lane*4. No ds_writes, no VGPR trip.
__device__ __forceinline__ void gload_lds4(const float* g, float* l) {
    __builtin_amdgcn_global_load_lds((const __attribute__((address_space(1))) void*)g,
                                     (__attribute__((address_space(3))) void*)l,
                                     4, 0, 0);
}

// STRIDE=95 (theta<90: bank ~ x-y, lane step |ca+sa| in [1,1.414])
// STRIDE=97 (theta>=90: bank ~ x+y, lane step |ca-sa| in [1,1.414])
template<int STRIDE>
__device__ __forceinline__ float tile_work(const float* __restrict__ img,
                                           float* __restrict__ tile,
                                           int lane, int wv,
                                           int iy0, int h, int a0x, int dB,
                                           float sa, float ca, float fx0, float fy0,
                                           int Ybase, bool interior) {
    // ---- stage bbox via async DMA: 2 full-wave 64-dword segments per row ----
    {
        const float* g = img + (size_t)(iy0 + wv) * N_IMG + a0x + lane;
        float* l = tile + wv * STRIDE;
        for (int r = wv; r < h; r += NWAVES) {
            gload_lds4(g, l);
            if (dB > 0) gload_lds4(g + dB, l + dB);
            g += NWAVES * N_IMG;
            l += NWAVES * STRIDE;
        }
    }
    __syncthreads();   // block-uniform path; drains vmcnt before reads

    float acc = 0.0f;
    const int base = -(iy0 * STRIDE + a0x);

    if (interior) {
        #pragma unroll
        for (int i = 0; i < TILE / NWAVES; ++i) {
            const float Yf   = (float)(Ybase + i);
            const float x_in = fmaf(sa, Yf, fx0);
            const float y_in = fmaf(ca, Yf, fy0);
            const float x0f = floorf(x_in);
            const float y0f = floorf(y_in);
            const float wx  = x_in - x0f;
            const float wy  = y_in - y0f;
            const int li = (int)y0f * STRIDE + (int)x0f + base;
            const float t00 = tile[li];             // ds_read2 (0,1)
            const float t01 = tile[li + 1];
            const float t10 = tile[li + STRIDE];    // ds_read2 (S,S+1)
            const float t11 = tile[li + STRIDE + 1];
            const float top = fmaf(wx, t01 - t00, t00);
            const float bot = fmaf(wx, t11 - t10, t10);
            acc += fmaf(wy, bot - top, top);
        }
    } else {
        #pragma unroll
        for (int i = 0; i < TILE / NWAVES; ++i) {
            const float Yf   = (float)(Ybase + i);
            const float x_in = fmaf(sa, Yf, fx0);
            const float y_in = fmaf(ca, Yf, fy0);
            const float x0f = floorf(x_in);
            const float y0f = floorf(y_in);
            const float wx  = x_in - x0f;
            const float wy  = y_in - y0f;
            const int x0 = (int)x0f;
            const int y0 = (int)y0f;
            const int x0c = min(max(x0,     0), N_IMG - 1);
            const int x1c = min(max(x0 + 1, 0), N_IMG - 1);
            const int y0c = min(max(y0,     0), N_IMG - 1);
            const int y1c = min(max(y0 + 1, 0), N_IMG - 1);
            const float wxa = (x0     >= 0 && x0     < N_IMG) ? (1.0f - wx) : 0.0f;
            const float wxb = (x0 + 1 >= 0 && x0 + 1 < N_IMG) ? wx          : 0.0f;
            const float wya = (y0     >= 0 && y0     < N_IMG) ? (1.0f - wy) : 0.0f;
            const float wyb = (y0 + 1 >= 0 && y0 + 1 < N_IMG) ? wy          : 0.0f;
            const int r0 = (y0c - iy0) * STRIDE - a0x;
            const int r1 = (y1c - iy0) * STRIDE - a0x;
            const float t00 = tile[r0 + x0c];
            const float t01 = tile[r0 + x1c];
            const float t10 = tile[r1 + x0c];
            const float t11 = tile[r1 + x1c];
            acc += wya * fmaf(wxa, t00, wxb * t01)
                 + wyb * fmaf(wxa, t10, wxb * t11);
        }
    }
    return acc;
}

__global__ __launch_bounds__(NTHREADS) void radon_tile(const float* __restrict__ img,
                                                       const float* __restrict__ theta,
                                                       float* __restrict__ partial,
                                                       float* __restrict__ out,
                                                       int mode) {
    __shared__ float tile[MAXH * MAXS];   // 35.7 KB -> 4 blocks/CU, 32 waves

    const int a  = blockIdx.z;
    const int X0 = blockIdx.x * TILE;
    const int Y0 = blockIdx.y * TILE;
    const int tid  = threadIdx.x;
    const int lane = tid & 63;
    const int wv   = tid >> 6;            // 0..7

    float* __restrict__ pslot = partial + ((size_t)(a * NYB + blockIdx.y) << 10) + X0;

    const float ang = theta[a] * 0.017453292519943295f;
    float sa, ca;
    __sincosf(ang, &sa, &ca);
    const float cx = (float)CENTER * (1.0f - ca - sa);
    const float cy = (float)CENTER * (1.0f - ca + sa);

    // ---- bbox from the 4 tile corners ----
    float x00, y00, x01, y01, x10, y10, x11, y11;
    map_coords(ca, sa, cx, cy, (float)X0,        (float)Y0,        x00, y00);
    map_coords(ca, sa, cx, cy, (float)(X0 + 63), (float)Y0,        x01, y01);
    map_coords(ca, sa, cx, cy, (float)X0,        (float)(Y0 + 63), x10, y10);
    map_coords(ca, sa, cx, cy, (float)(X0 + 63), (float)(Y0 + 63), x11, y11);
    const float xmin = fminf(fminf(x00, x01), fminf(x10, x11));
    const float xmax = fmaxf(fmaxf(x00, x01), fmaxf(x10, x11));
    const float ymin = fminf(fminf(y00, y01), fminf(y10, y11));
    const float ymax = fmaxf(fmaxf(y00, y01), fmaxf(y10, y11));

    const int ix0_raw = (int)floorf(xmin);
    const int ix1_raw = (int)floorf(xmax) + 1;
    const int iy0_raw = (int)floorf(ymin);
    const int iy1_raw = (int)floorf(ymax) + 1;

    const int ix0 = max(0, ix0_raw);
    const int ix1 = min(N_IMG - 1, ix1_raw);
    const int iy0 = max(0, iy0_raw);
    const int iy1 = min(N_IMG - 1, iy1_raw);

    if (ix1 < ix0 || iy1 < iy0) {          // tile maps fully outside image
        if (mode == 0) { if (tid < 64) pslot[tid] = 0.0f; }
        return;                             // mode 1: out pre-zeroed
    }

    // ---- two full-wave 64-dword column segments (always in-image, no masking)
    const int a0x = min(ix0, N_IMG - 64);
    const int b0x = max(a0x, ix1 - 63);
    const int dB  = b0x - a0x;              // 0..28 -> used width <= 92 < STRIDE
    const int h   = iy1 - iy0 + 1;          // <= 92

    const int X = X0 + lane;
    const float Xf  = (float)X;
    const float fx0 = fmaf(ca, Xf, cx);
    const float fy0 = fmaf(-sa, Xf, cy);
    const int Ybase = Y0 + wv * (TILE / NWAVES);

    const bool interior = (ix0_raw >= 0) && (ix1_raw <= N_IMG - 1) &&
                          (iy0_raw >= 0) && (iy1_raw <= N_IMG - 1);

    // Block-uniform branch: theta<90 (ca>0) -> stride 95; else stride 97.
    float acc;
    if (ca > 0.0f)
        acc = tile_work<95>(img, tile, lane, wv, iy0, h, a0x, dB,
                            sa, ca, fx0, fy0, Ybase, interior);
    else
        acc = tile_work<97>(img, tile, lane, wv, iy0, h, a0x, dB,
                            sa, ca, fx0, fy0, Ybase, interior);

    // ---- block reduce, overlaying tile (saves LDS); plain store or atomic ----
    __syncthreads();                        // all waves done reading tile
    tile[wv * 64 + lane] = acc;
    __syncthreads();
    if (wv == 0) {
        float s = 0.0f;
        #pragma unroll
        for (int w = 0; w < NWAVES; ++w) s += tile[w * 64 + lane];
        if (mode == 0) pslot[lane] = s;
        else           atomicAdd(&out[X * N_VIEWS + a], s);
    }
}

__global__ __launch_bounds__(256) void reduce_partials(const float* __restrict__ partial,
                                                       float* __restrict__ out) {
    const int g = blockIdx.x * 256 + threadIdx.x;   // [0, 90*1024)
    const int a = g >> 10;
    const int X = g & 1023;
    float s = 0.0f;
    #pragma unroll
    for (int yb = 0; yb < NYB; ++yb)
        s += partial[((size_t)(a * NYB + yb) << 10) + X];
    out[X * N_VIEWS + a] = s;
}

extern "C" void kernel_launch(void* const* d_in, const int* in_sizes, int n_in,
                              void* d_out, int out_size, void* d_ws, size_t ws_size,
                              hipStream_t stream) {
    const float* img   = (const float*)d_in[0];   // [1024, 1024] f32
    const float* theta = (const float*)d_in[1];   // [90] f32 degrees
    float* out     = (float*)d_out;               // [1024, 90] f32
    float* partial = (float*)d_ws;                // [90][16][1024] f32 partials

    const size_t needed = (size_t)N_VIEWS * NYB * N_IMG * sizeof(float);  // 5.9 MB
    const int mode = (ws_size >= needed) ? 0 : 1;
    if (mode == 1)
        hipMemsetAsync(d_out, 0, (size_t)out_size * sizeof(float), stream);

    dim3 grid(N_IMG / TILE, N_IMG / TILE, N_VIEWS);   // 16 x 16 x 90, one dispatch
    radon_tile<<<grid, NTHREADS, 0, stream>>>(img, theta, partial, out, mode);

    if (mode == 0)
        reduce_partials<<<(N_VIEWS * N_IMG) / 256, 256, 0, stream>>>(partial, out);
}